// Round 2
// 125.799 us; speedup vs baseline: 1.0203x; 1.0203x over previous
//
#include <hip/hip_runtime.h>
#include <math.h>

#define B_ 8
#define N_ 16384
#define M_ 128
#define C_ 81
#define TPB 512
#define KPT 32              // keys per thread = N_/TPB
#define NWAVE (TPB / 64)    // 8
#define ABLK 32             // iou blocks per image (N_/512)
#define ATPB 512

// ============ Kernel A: GT hbb prep + IoU + argmax + key emit + counts ======
// Writes: poskey[b][n], negkey[b][n] (u32 order keys, 0xFFFFFFFF sentinel),
//         match8[b][n] (u8 argmax GT), cnt[b][blk] = pos_count | zero_count<<16
__global__ __launch_bounds__(ATPB)
void iou_fused(const float* __restrict__ bp,     // [B,N,5]
               const float* __restrict__ rt,     // [B,M,4,2]
               unsigned* __restrict__ poskey,    // [B,N]
               unsigned* __restrict__ negkey,    // [B,N]
               unsigned char* __restrict__ match8, // [B,N]
               unsigned* __restrict__ cnt,       // [B,ABLK]
               float* __restrict__ out) {        // [3] zeroed here
    __shared__ float sx1[M_], sy1[M_], sx2[M_], sy2[M_], sab[M_];
    __shared__ unsigned scnt[ATPB / 64];
    int b = blockIdx.y;
    int n = blockIdx.x * ATPB + threadIdx.x;

    if (blockIdx.x == 0 && blockIdx.y == 0 && threadIdx.x < 3)
        out[threadIdx.x] = 0.0f;

    if (threadIdx.x < M_) {
        const float* v = rt + ((size_t)b * M_ + threadIdx.x) * 8;
        float x0 = v[0], y0 = v[1], x1 = v[2], y1 = v[3];
        float x2 = v[4], y2 = v[5], x3 = v[6], y3 = v[7];
        float mnx = fminf(fminf(x0, x1), fminf(x2, x3));
        float mny = fminf(fminf(y0, y1), fminf(y2, y3));
        float mxx = fmaxf(fmaxf(x0, x1), fmaxf(x2, x3));
        float mxy = fmaxf(fmaxf(y0, y1), fmaxf(y2, y3));
        sx1[threadIdx.x] = mnx; sy1[threadIdx.x] = mny;
        sx2[threadIdx.x] = mxx; sy2[threadIdx.x] = mxy;
        sab[threadIdx.x] = (mxx - mnx) * (mxy - mny);
    }
    __syncthreads();

    const float* p = bp + ((size_t)b * N_ + n) * 5;
    float cx = p[0], cy = p[1], w = p[2], h = p[3], a = p[4];
    float c = cosf(a), s = sinf(a);
    float dx = w * 0.5f, dy = h * 0.5f;
    float ex = fabsf(dx * c) + fabsf(dy * s);
    float ey = fabsf(dx * s) + fabsf(dy * c);
    float ax1 = cx - ex, ay1 = cy - ey, ax2 = cx + ex, ay2 = cy + ey;
    float area_a = (ax2 - ax1) * (ay2 - ay1);

    // division-free argmax: best tracked as (inter, uni) pair, init -1/1
    float bin = -1.0f, bun = 1.0f;
    int bm = 0;
#pragma unroll 4
    for (int m = 0; m < M_; m++) {
        float lx = fmaxf(ax1, sx1[m]), ly = fmaxf(ay1, sy1[m]);
        float rx = fminf(ax2, sx2[m]), ry = fminf(ay2, sy2[m]);
        float ww = fmaxf(rx - lx, 0.0f), hh = fmaxf(ry - ly, 0.0f);
        float inter = ww * hh;
        float uni = area_a + sab[m] - inter;   // >= GT hbb area >= 256 > 0 always
        bool better = inter * bun > bin * uni; // iou_m > best (uni>0)
        bin = better ? inter : bin;
        bun = better ? uni : bun;
        bm = better ? m : bm;
    }
    float iou = bin / bun;
    unsigned bits = __float_as_uint(iou);
    bool pos = (iou >= 0.5f);
    size_t gi = (size_t)b * N_ + n;
    poskey[gi] = pos ? ~(bits | 0x80000000u) : 0xFFFFFFFFu;  // asc key = iou desc
    negkey[gi] = pos ? 0xFFFFFFFFu : (bits | 0x80000000u);   // asc key = iou asc
    match8[gi] = (unsigned char)bm;

    // per-block packed counts (own slot -> poisoned ws needs no init)
    unsigned posb = (unsigned)__popcll(__ballot(pos));
    unsigned zerb = (unsigned)__popcll(__ballot(bits == 0u)); // iou==+0 => negative
    int lane = threadIdx.x & 63, wv = threadIdx.x >> 6;
    if (lane == 0) scnt[wv] = posb | (zerb << 16);
    __syncthreads();
    if (threadIdx.x == 0) {
        unsigned t = 0;
#pragma unroll
        for (int i = 0; i < ATPB / 64; i++) t += scnt[i];
        cnt[(size_t)b * ABLK + blockIdx.x] = t;
    }
}

// ============ ballot-based block sum (c <= 63), no shuffles ============
__device__ __forceinline__ unsigned wave_sum6(unsigned c) {
    unsigned s = 0;
#pragma unroll
    for (int bit = 0; bit < 6; bit++)
        s += (unsigned)__popcll(__ballot((c >> bit) & 1u)) << bit;
    return s;
}

__device__ __forceinline__ unsigned bsum(unsigned c, unsigned* slot) {
    unsigned ws = wave_sum6(c);
    if ((threadIdx.x & 63) == 0) slot[threadIdx.x >> 6] = ws;
    __syncthreads();
    unsigned r = 0;
#pragma unroll
    for (int i = 0; i < NWAVE; i++) r += slot[i];
    return r;
}

// ============ Kernel B: exact top-k selection + loss + atomic out ============
// blockIdx.x: 0 = positives (iou desc, idx asc), 1 = negatives (iou asc, idx asc)
__global__ __launch_bounds__(TPB)
void select_loss(const unsigned* __restrict__ keys_pos,
                 const unsigned* __restrict__ keys_neg,
                 const unsigned char* __restrict__ match8,
                 const float* __restrict__ logits, const float* __restrict__ bp,
                 const float* __restrict__ rt, const int* __restrict__ labels,
                 const int* __restrict__ ns_ptr, const unsigned* __restrict__ cnt,
                 float* __restrict__ out) {
    int type = blockIdx.x;
    int b = blockIdx.y;
    __shared__ float s_cv2[5][M_];
    __shared__ unsigned red[2 * NWAVE] __attribute__((aligned(16)));
    __shared__ float fredc[NWAVE], fredr[NWAVE];
    __shared__ unsigned sel[256];
    __shared__ unsigned selcnt;
    __shared__ unsigned s_tot;

    int tid = threadIdx.x;
    int lane = tid & 63, wv = tid >> 6;
    if (tid == 0) selcnt = 0;

    // ---- issue key loads first (latency-hidden under staging) ----
    const unsigned* kb = (type == 0) ? keys_pos : keys_neg;
    const uint4* k4 = (const uint4*)(kb + (size_t)b * N_);
    uint4 kv[KPT / 4];
#pragma unroll
    for (int q = 0; q < KPT / 4; q++) kv[q] = k4[tid * (KPT / 4) + q];

    if (type == 0 && tid < M_) {
        const float* v = rt + ((size_t)b * M_ + tid) * 8;
        float x0 = v[0], y0 = v[1], x1 = v[2], y1 = v[3];
        float x2 = v[4], y2 = v[5], x3 = v[6], y3 = v[7];
        s_cv2[0][tid] = (x0 + x1 + x2 + x3) * 0.25f;
        s_cv2[1][tid] = (y0 + y1 + y2 + y3) * 0.25f;
        float e1x = x1 - x0, e1y = y1 - y0;
        float e2x = x3 - x0, e2y = y3 - y0;
        s_cv2[2][tid] = sqrtf(e1x * e1x + e1y * e1y);
        s_cv2[3][tid] = sqrtf(e2x * e2x + e2y * e2y);
        s_cv2[4][tid] = atan2f(e1y, e1x);
    }

    // ---- per-image counts: one coalesced load + wave reduce (no bsum) ----
    if (wv == 0) {
        unsigned c = (lane < ABLK) ? cnt[(size_t)b * ABLK + lane] : 0u;
#pragma unroll
        for (int o = 1; o < 64; o <<= 1) c += __shfl_xor(c, o);
        if (lane == 0) s_tot = c;
    }

    int ns = ns_ptr[0];
    unsigned ktar = (type == 0) ? (unsigned)(ns / 2) : (unsigned)(ns - ns / 2);
    if (ktar > 256u) ktar = 256u;

    unsigned key[KPT];
#pragma unroll
    for (int q = 0; q < KPT / 4; q++) {
        key[q * 4 + 0] = kv[q].x; key[q * 4 + 1] = kv[q].y;
        key[q * 4 + 2] = kv[q].z; key[q * 4 + 3] = kv[q].w;
    }
    int base = tid * KPT;

    __syncthreads();  // selcnt + s_cv2 + s_tot visible

    unsigned tot = s_tot;
    unsigned pos_total = tot & 0xFFFFu;
    unsigned zero_total = tot >> 16;
    unsigned V = (type == 0) ? pos_total : (unsigned)N_ - pos_total;
    unsigned keff = (ktar < V) ? ktar : V;

    int pc = 0;
    if (keff == V) {
        // fast path: every valid item selected (order irrelevant — sum)
#pragma unroll
        for (int j = 0; j < KPT; j++) {
            if (key[j] != 0xFFFFFFFFu) {
                unsigned p = atomicAdd(&selcnt, 1u);
                sel[p] = (unsigned)(base + j);
            }
        }
    } else {
        unsigned Ckey, m;
        bool zshort = (type == 1) && (zero_total >= keff);
        if (zshort) {
            // >=keff boxes with iou==0: threshold is the minimum possible key
            Ckey = 0x80000000u;
            m = 0u;           // nothing strictly below 0x80000000
        } else {
            // binary search, bounds tightened per type's key range
            unsigned lo = (type == 0) ? 0x40000000u : 0x80000000u;
            unsigned hi = (type == 0) ? 0x41000000u : 0xC0000000u;
            while (lo < hi) {
                unsigned mid = lo + ((hi - lo) >> 1);
                unsigned c = 0;
#pragma unroll
                for (int j = 0; j < KPT; j++) c += (key[j] <= mid) ? 1u : 0u;
                unsigned t2 = bsum(c, red + NWAVE * ((pc++) & 1));
                if (t2 >= keff) hi = mid; else lo = mid + 1;
            }
            Ckey = lo;
            unsigned cl = 0;
#pragma unroll
            for (int j = 0; j < KPT; j++) cl += (key[j] < Ckey) ? 1u : 0u;
            m = bsum(cl, red + NWAVE * ((pc++) & 1));
        }
        unsigned e = keff - m;  // ties to take, ascending index

        unsigned ce = 0;
#pragma unroll
        for (int j = 0; j < KPT; j++) ce += (key[j] == Ckey) ? 1u : 0u;

        // rank of this thread's first tie: wave prefix + cross-wave offset
        unsigned sc = ce;
#pragma unroll
        for (int o = 1; o < 64; o <<= 1) {
            unsigned t = __shfl_up(sc, o);
            if (lane >= o) sc += t;
        }
        unsigned* slot = red + NWAVE * ((pc++) & 1);
        if (lane == 63) slot[wv] = sc;
        __syncthreads();
        unsigned off = 0;
        for (int i = 0; i < wv; i++) off += slot[i];
        unsigned rank = off + sc - ce;

#pragma unroll
        for (int j = 0; j < KPT; j++) {
            unsigned k = key[j];
            bool s = false;
            if (k < Ckey) s = true;
            else if (k == Ckey) { s = (rank < e); rank++; }
            if (s) {
                unsigned p = atomicAdd(&selcnt, 1u);
                sel[p] = (unsigned)(base + j);
            }
        }
    }
    __syncthreads();
    unsigned total_sel = selcnt;  // == keff

    // ---- loss: 4 threads per sample, 21 logits each ----
    float cls_sum = 0.f, reg_sum = 0.f;
    int q = tid & 3;
    for (unsigned sm = (unsigned)(tid >> 2); sm < total_sel; sm += TPB / 4) {
        unsigned i = sel[sm];
        const float* row = logits + ((size_t)b * N_ + i) * C_;
        int c0 = q * 21;
        int c1 = (c0 + 21 < C_) ? c0 + 21 : C_;
        float mx = -INFINITY;
        for (int c = c0; c < c1; c++) mx = fmaxf(mx, row[c]);
        mx = fmaxf(mx, __shfl_xor(mx, 1));
        mx = fmaxf(mx, __shfl_xor(mx, 2));
        float se = 0.f;
        for (int c = c0; c < c1; c++) se += expf(row[c] - mx);
        se += __shfl_xor(se, 1);
        se += __shfl_xor(se, 2);
        if (q == 0) {
            float lse = mx + logf(se);
            if (type == 0) {
                int g_gt = (int)match8[(size_t)b * N_ + i];
                int tc = labels[b * M_ + g_gt];
                cls_sum += lse - row[tc];
                const float* pp = bp + ((size_t)b * N_ + i) * 5;
#pragma unroll
                for (int d = 0; d < 5; d++) {
                    float ad = fabsf(pp[d] - s_cv2[d][g_gt]);
                    reg_sum += (ad < 1.f) ? 0.5f * ad * ad : ad - 0.5f;
                }
            } else {
                cls_sum += lse - row[C_ - 1];
            }
        }
    }

    // ---- final reduce: interleaved shfl chains + single barrier ----
#pragma unroll
    for (int o = 32; o; o >>= 1) {
        cls_sum += __shfl_down(cls_sum, o);
        reg_sum += __shfl_down(reg_sum, o);
    }
    if (lane == 0) { fredc[wv] = cls_sum; fredr[wv] = reg_sum; }
    __syncthreads();
    if (tid == 0) {
        float cs = 0.f, rs = 0.f;
#pragma unroll
        for (int i = 0; i < NWAVE; i++) { cs += fredc[i]; rs += fredr[i]; }
        const float invB = 1.0f / (float)B_;
        atomicAdd(&out[0], (cs + rs) * invB);
        atomicAdd(&out[1], cs * invB);
        atomicAdd(&out[2], rs * invB);
    }
}

extern "C" void kernel_launch(void* const* d_in, const int* in_sizes, int n_in,
                              void* d_out, int out_size, void* d_ws, size_t ws_size,
                              hipStream_t stream) {
    const float* box_pred = (const float*)d_in[0];     // [B,N,5]
    const float* class_pred = (const float*)d_in[1];   // [B,N,C]
    const float* reg_tgt = (const float*)d_in[2];      // [B,M,4,2]
    const int* cls_tgt = (const int*)d_in[3];          // [B,M]
    const int* n_samples = (const int*)d_in[4];        // [1]

    unsigned* poskey = (unsigned*)d_ws;                         // B*N u32
    unsigned* negkey = poskey + (size_t)B_ * N_;                // B*N u32
    unsigned* cnt = negkey + (size_t)B_ * N_;                   // B*ABLK u32
    unsigned char* match8 = (unsigned char*)(cnt + B_ * ABLK);  // B*N u8
    float* out = (float*)d_out;

    iou_fused<<<dim3(ABLK, B_), ATPB, 0, stream>>>(box_pred, reg_tgt, poskey,
                                                   negkey, match8, cnt, out);
    select_loss<<<dim3(2, B_), TPB, 0, stream>>>(poskey, negkey, match8,
                                                 class_pred, box_pred, reg_tgt,
                                                 cls_tgt, n_samples, cnt, out);
}